// Round 11
// baseline (92.052 us; speedup 1.0000x reference)
//
#include <hip/hip_runtime.h>

// UCBNorm, TWO kernels - clean 2-node test (r8's version was confounded by an
// expensive block-redundant finalize; this one costs ~1.5us via TCH=1 partials).
//
// Math (softmax(prior) over size-1 axis == 1 -> constant 1/sqrt(1+EPS)):
//   p_k = exp2(qa x^2 + qb x + qc)   (log2e folded into the quadratic coeffs)
//   den = EPS + sum_k p,  tau = p/den,  S[k,d] = EPS + sum_{b,t} tau
//   e = (sum_t tau x)/(T S),  var = (sum_t tau^3 x^2)/(T S^3)
//   out = (1/sqrt(1+EPS)) * rden * (x * sum_k p r_k - sum_k p e_k r_k)
//
// k1: 256 blocks (b, 16-d slice) covering FULL T; 16d x 16tp threads, LDS
//     tree over tp -> partials [K][B][D] (3 x 128 KB, no tch dimension).
// k2: 256 blocks (b, 32-t chunk) x 512 thr; block-redundant finalize of all
//     2048 (k,d) = 18 coalesced loads each -> LDS (r, e*r); then main loop.

namespace {
constexpr int K = 8, B = 16, T = 512, D = 256;
constexpr float EPS = 1e-3f;
constexpr float LOG2E = 1.4426950408889634f;
constexpr int DSL = 16;              // d per slice in k1
constexpr int NSL = D / DSL;         // 16 slices
constexpr int TP  = 16;              // t-parallel threads in k1
constexpr int RT  = T / TP;          // 32 t-iters per thread
constexpr int KS  = 3 * K;           // 24
constexpr int PSZ = K * B * D;       // 32768 floats per partial array
}

__global__ __launch_bounds__(256) void ucb_k1(
    const float* __restrict__ x, const float* __restrict__ mean,
    const float* __restrict__ variance,
    float* __restrict__ pt, float* __restrict__ p1s, float* __restrict__ p3s)
{
  __shared__ float red[TP][DSL][KS + 1];   // 25.6 KB, stride 25

  const int tid = threadIdx.x;
  const int dl  = tid & 15;
  const int tp  = tid >> 4;
  const int b   = blockIdx.x >> 4;
  const int sl  = blockIdx.x & 15;
  const int dd  = sl*DSL + dl;

  float qa[K], qb[K], qc[K];
#pragma unroll
  for (int k = 0; k < K; ++k) {
    float mk = mean[k*D + dd];
    float sp = log1pf(__expf(variance[k*D + dd]));   // softplus
    float nh = -0.5f * LOG2E / (sp + EPS);           // log2e folded in
    qa[k] = nh; qb[k] = -2.0f*nh*mk; qc[k] = nh*mk*mk;
  }

  float ast[K], as1[K], as3[K];
#pragma unroll
  for (int k = 0; k < K; ++k) { ast[k]=0.f; as1[k]=0.f; as3[k]=0.f; }

  // t = tp + TP*j  (full T per block)
  const float* xp = x + ((size_t)b*T + tp)*D + dd;
#pragma unroll 4
  for (int j = 0; j < RT; ++j) {
    float xv = xp[(size_t)j*TP*D];
    float x2 = xv*xv;
    float p[K];
#pragma unroll
    for (int k = 0; k < K; ++k)
      p[k] = exp2f(fmaf(qa[k], x2, fmaf(qb[k], xv, qc[k])));
    float den = EPS + ((p[0]+p[1])+(p[2]+p[3])) + ((p[4]+p[5])+(p[6]+p[7]));
    float rden = __builtin_amdgcn_rcpf(den);
#pragma unroll
    for (int k = 0; k < K; ++k) {
      float tau = p[k]*rden;
      float tx  = tau*xv;
      ast[k] += tau;
      as1[k] += tx;
      as3[k]  = fmaf(tx*tx, tau, as3[k]);   // tau^3 x^2
    }
  }

#pragma unroll
  for (int k = 0; k < K; ++k) {
    red[tp][dl][3*k+0] = ast[k];
    red[tp][dl][3*k+1] = as1[k];
    red[tp][dl][3*k+2] = as3[k];
  }
  __syncthreads();

#pragma unroll
  for (int i = 0; i < 2; ++i) {            // 384 items
    const int item = tid + i*256;
    if (item < DSL*KS) {
      const int dloc = item / KS;
      const int ks   = item % KS;
      float s = 0.f;
#pragma unroll
      for (int t2 = 0; t2 < TP; ++t2) s += red[t2][dloc][ks];
      const int k = ks / 3, stat = ks % 3;
      const size_t idx = ((size_t)(k*B + b))*D + sl*DSL + dloc;
      if      (stat == 0) pt [idx] = s;
      else if (stat == 1) p1s[idx] = s;
      else                p3s[idx] = s;
    }
  }
}

__global__ __launch_bounds__(512) void ucb_k2(
    const float* __restrict__ x, const float* __restrict__ mean,
    const float* __restrict__ variance,
    const float* __restrict__ pt, const float* __restrict__ p1s,
    const float* __restrict__ p3s, float* __restrict__ out)
{
  __shared__ float rr_l[K][D];     // r    (8 KB)
  __shared__ float erc_l[K][D];    // e*r  (8 KB)

  const int tid = threadIdx.x;
  const int b   = blockIdx.x >> 4;
  const int tc  = blockIdx.x & 15;         // 16 chunks x 32 t

  // ---- block-redundant finalize: 2048 (k,d) items, 4/thread, 18 loads each
  const float rT = 1.0f / T;
#pragma unroll
  for (int i = 0; i < 4; ++i) {
    const int item = tid + i*512;
    const int d = item & 255;
    const int k = item >> 8;
    float S = EPS;
#pragma unroll
    for (int bb = 0; bb < B; ++bb)
      S += pt[((size_t)(k*B + bb))*D + d];
    const size_t ib = ((size_t)(k*B + b))*D + d;
    const float a1 = p1s[ib];
    const float a3 = p3s[ib];
    const float rS = 1.0f / S;
    const float e  = a1 * rT * rS;
    const float vv = a3 * rT * (rS*rS*rS);
    const float r  = rsqrtf(vv + EPS);
    rr_l[k][d]  = r;
    erc_l[k][d] = e * r;
  }
  __syncthreads();

  // ---- main loop: 32 t per block, thread = (t2, d) ----
  const int d  = tid & 255;
  const int t2 = tid >> 8;                 // 0..1

  float qa[K], qb[K], qc[K], rr[K], erc[K];
#pragma unroll
  for (int k = 0; k < K; ++k) {
    float mk = mean[k*D + d];
    float sp = log1pf(__expf(variance[k*D + d]));
    float nh = -0.5f * LOG2E / (sp + EPS);
    qa[k] = nh; qb[k] = -2.0f*nh*mk; qc[k] = nh*mk*mk;
    rr[k]  = rr_l[k][d];
    erc[k] = erc_l[k][d];
  }

  const float isp = 0.99950037f;           // 1/sqrt(1+EPS)
  // t = tc*32 + j*2 + t2
  const size_t base = ((size_t)b*T + (size_t)tc*32 + t2)*D + d;
#pragma unroll 4
  for (int j = 0; j < 16; ++j) {
    float xv = x[base + (size_t)(j*2)*D];
    float x2 = xv*xv;
    float p[K];
#pragma unroll
    for (int k = 0; k < K; ++k)
      p[k] = exp2f(fmaf(qa[k], x2, fmaf(qb[k], xv, qc[k])));
    float den = EPS + ((p[0]+p[1])+(p[2]+p[3])) + ((p[4]+p[5])+(p[6]+p[7]));
    float rden = __builtin_amdgcn_rcpf(den);
    float acc1 = 0.f, acc2 = 0.f;
#pragma unroll
    for (int k = 0; k < K; ++k) {
      acc1 = fmaf(p[k], rr[k],  acc1);     // sum p*r
      acc2 = fmaf(p[k], erc[k], acc2);     // sum p*e*r
    }
    out[base + (size_t)(j*2)*D] = (xv*acc1 - acc2) * rden * isp;
  }
}

extern "C" void kernel_launch(void* const* d_in, const int* in_sizes, int n_in,
                              void* d_out, int out_size, void* d_ws, size_t ws_size,
                              hipStream_t stream) {
  const float* x        = (const float*)d_in[0];
  const float* mean     = (const float*)d_in[1];
  const float* variance = (const float*)d_in[2];
  // d_in[3] (prior): softmax over size-1 axis == 1 -> constant baked in.

  float* out = (float*)d_out;
  float* w   = (float*)d_ws;
  float* pt  = w;            // [K][B][D] = 32768 floats each
  float* p1s = pt  + PSZ;
  float* p3s = p1s + PSZ;
  // every ws element is written before it is read -> no memset needed

  ucb_k1<<<B*NSL, 256, 0, stream>>>(x, mean, variance, pt, p1s, p3s);
  ucb_k2<<<B*16,  512, 0, stream>>>(x, mean, variance, pt, p1s, p3s, out);
}

// Round 12
// 85.906 us; speedup vs baseline: 1.0715x; 1.0715x over previous
//
#include <hip/hip_runtime.h>

// UCBNorm, 3 kernels — r7 configuration verbatim (best measured: 85.1 us).
// Five structural variants (1/2/3-node, TLP, coalescing, traffic shrink)
// cluster 85-92 us; totals are dominated by the harness envelope (256 MiB
// ws-poison fill ~43 us at ~80% HBM peak + ~30 us graph overhead). Our
// kernels sum to ~7-10 us vs ~7 us arithmetic floor.
//
// Math (softmax(prior) over size-1 axis == 1 -> constant 1/sqrt(1+EPS)):
//   p_k = exp(qa x^2 + qb x + qc)  (expanded -0.5(x-m)^2/(softplus(v)+EPS))
//   den = EPS + sum_k p,  tau = p/den,  S[k,d] = EPS + sum_{b,t} tau
//   e = (sum_t tau x)/(T S),  var = (sum_t tau^3 x^2)/(T S^3)
//   out = (1/sqrt(1+EPS)) * rden * (x * sum_k p r_k - sum_k p e_k r_k)
//
// k1:  512 blocks (b, 16-d slice, T-half); LDS tree over 16 t-parallel lanes
//      -> partials [2][K][B][D] (768 KB).
// fin: 128 blocks; per (k,b,d) 6 coalesced loads; cross-b S via LDS.
// k2:  1024 blocks (b, 8-t chunk) x 256 d; recompute p, factored epilogue.

namespace {
constexpr int K = 8, B = 16, T = 512, D = 256;
constexpr float EPS = 1e-3f;
constexpr int DSL = 16;              // d per slice in k1
constexpr int NSL = D / DSL;         // 16 slices
constexpr int TCH = 2;               // t-chunks in k1
constexpr int TLC = T / TCH;         // 256 t per chunk
constexpr int TP  = 16;              // t-parallel threads
constexpr int RT  = TLC / TP;        // 16 t-iters per thread
constexpr int KS  = 3 * K;           // 24
constexpr int PSZ = TCH * K * B * D; // 65536 floats per partial array
}

__global__ __launch_bounds__(256) void ucb_k1(
    const float* __restrict__ x, const float* __restrict__ mean,
    const float* __restrict__ variance,
    float* __restrict__ pt, float* __restrict__ p1s, float* __restrict__ p3s)
{
  __shared__ float red[TP][DSL][KS + 1];   // 25.6 KB, stride 25

  const int tid = threadIdx.x;
  const int dl  = tid & 15;
  const int tp  = tid >> 4;
  const int bi  = blockIdx.x;
  const int b   = bi >> 5;
  const int sl  = (bi >> 1) & 15;
  const int tch = bi & 1;
  const int dd  = sl*DSL + dl;

  float qa[K], qb[K], qc[K];
#pragma unroll
  for (int k = 0; k < K; ++k) {
    float mk = mean[k*D + dd];
    float sp = log1pf(__expf(variance[k*D + dd]));   // softplus
    float nh = -0.5f / (sp + EPS);
    qa[k] = nh; qb[k] = -2.0f*nh*mk; qc[k] = nh*mk*mk;
  }

  float ast[K], as1[K], as3[K];
#pragma unroll
  for (int k = 0; k < K; ++k) { ast[k]=0.f; as1[k]=0.f; as3[k]=0.f; }

  // t = tch*TLC + tp + TP*j
  const float* xp = x + ((size_t)b*T + (size_t)tch*TLC + tp)*D + dd;
#pragma unroll 4
  for (int j = 0; j < RT; ++j) {
    float xv = xp[(size_t)j*TP*D];
    float x2 = xv*xv;
    float p[K];
#pragma unroll
    for (int k = 0; k < K; ++k)
      p[k] = __expf(fmaf(qa[k], x2, fmaf(qb[k], xv, qc[k])));
    float den = EPS + ((p[0]+p[1])+(p[2]+p[3])) + ((p[4]+p[5])+(p[6]+p[7]));
    float rden = __builtin_amdgcn_rcpf(den);
#pragma unroll
    for (int k = 0; k < K; ++k) {
      float tau = p[k]*rden;
      float tx  = tau*xv;
      ast[k] += tau;
      as1[k] += tx;
      as3[k]  = fmaf(tx*tx, tau, as3[k]);   // tau^3 x^2
    }
  }

#pragma unroll
  for (int k = 0; k < K; ++k) {
    red[tp][dl][3*k+0] = ast[k];
    red[tp][dl][3*k+1] = as1[k];
    red[tp][dl][3*k+2] = as3[k];
  }
  __syncthreads();

#pragma unroll
  for (int i = 0; i < 2; ++i) {            // 384 items
    const int item = tid + i*256;
    if (item < DSL*KS) {
      const int dloc = item / KS;
      const int ks   = item % KS;
      float s = 0.f;
#pragma unroll
      for (int t2 = 0; t2 < TP; ++t2) s += red[t2][dloc][ks];
      const int k = ks / 3, stat = ks % 3;
      const size_t idx = ((size_t)((tch*K + k)*B + b))*D + sl*DSL + dloc;
      if      (stat == 0) pt [idx] = s;
      else if (stat == 1) p1s[idx] = s;
      else                p3s[idx] = s;
    }
  }
}

__global__ __launch_bounds__(256) void ucb_fin(
    const float* __restrict__ pt, const float* __restrict__ p1s,
    const float* __restrict__ p3s, float* __restrict__ er)  // [B][K][2][D]
{
  // 128 blocks: (k, 16-d group); 256 thr = 16 b x 16 d
  __shared__ float reds[B][17];

  const int k  = blockIdx.x >> 4;
  const int d0 = (blockIdx.x & 15) * 16;
  const int dl = threadIdx.x & 15;
  const int bb = threadIdx.x >> 4;
  const int d  = d0 + dl;

  const size_t i0 = ((size_t)(k*B + bb))*D + d;          // tch=0
  const size_t i1 = i0 + (size_t)K*B*D;                  // tch=1
  const float a0 = pt [i0] + pt [i1];
  const float a1 = p1s[i0] + p1s[i1];
  const float a3 = p3s[i0] + p3s[i1];

  reds[bb][dl] = a0;
  __syncthreads();
  if (threadIdx.x < 16) {
    float s = 0.f;
#pragma unroll
    for (int b2 = 0; b2 < B; ++b2) s += reds[b2][threadIdx.x];
    reds[0][threadIdx.x] = 1.0f / (s + EPS);             // rS
  }
  __syncthreads();

  const float rS = reds[0][dl];
  const float rT = 1.0f / T;
  const float e  = a1 * rT * rS;
  const float vv = a3 * rT * (rS*rS*rS);
  const float r  = rsqrtf(vv + EPS);
  er[((size_t)(bb*K + k)*2 + 0)*D + d] = e;
  er[((size_t)(bb*K + k)*2 + 1)*D + d] = r;
}

__global__ __launch_bounds__(256) void ucb_k2(
    const float* __restrict__ x, const float* __restrict__ mean,
    const float* __restrict__ variance, const float* __restrict__ er,
    float* __restrict__ out)
{
  const int d  = threadIdx.x;
  const int b  = blockIdx.x >> 6;
  const int tc = blockIdx.x & 63;          // 64 chunks x 8 t

  float qa[K], qb[K], qc[K], rr[K], erc[K];
#pragma unroll
  for (int k = 0; k < K; ++k) {
    float mk = mean[k*D + d];
    float sp = log1pf(__expf(variance[k*D + d]));
    float nh = -0.5f / (sp + EPS);
    qa[k] = nh; qb[k] = -2.0f*nh*mk; qc[k] = nh*mk*mk;
    float e = er[((size_t)(b*K + k)*2 + 0)*D + d];
    float r = er[((size_t)(b*K + k)*2 + 1)*D + d];
    rr[k] = r; erc[k] = e*r;
  }

  const float isp = 0.99950037f;           // 1/sqrt(1+EPS)
  const size_t base = ((size_t)b*T + (size_t)tc*8)*D + d;
#pragma unroll
  for (int t = 0; t < 8; ++t) {
    float xv = x[base + (size_t)t*D];
    float x2 = xv*xv;
    float p[K];
#pragma unroll
    for (int k = 0; k < K; ++k)
      p[k] = __expf(fmaf(qa[k], x2, fmaf(qb[k], xv, qc[k])));
    float den = EPS + ((p[0]+p[1])+(p[2]+p[3])) + ((p[4]+p[5])+(p[6]+p[7]));
    float rden = __builtin_amdgcn_rcpf(den);
    float acc1 = 0.f, acc2 = 0.f;
#pragma unroll
    for (int k = 0; k < K; ++k) {
      acc1 = fmaf(p[k], rr[k],  acc1);     // sum p*r
      acc2 = fmaf(p[k], erc[k], acc2);     // sum p*e*r
    }
    out[base + (size_t)t*D] = (xv*acc1 - acc2) * rden * isp;
  }
}

extern "C" void kernel_launch(void* const* d_in, const int* in_sizes, int n_in,
                              void* d_out, int out_size, void* d_ws, size_t ws_size,
                              hipStream_t stream) {
  const float* x        = (const float*)d_in[0];
  const float* mean     = (const float*)d_in[1];
  const float* variance = (const float*)d_in[2];
  // d_in[3] (prior): softmax over size-1 axis == 1 -> constant baked in.

  float* out = (float*)d_out;
  float* w   = (float*)d_ws;
  float* pt  = w;            // [TCH][K][B][D] = 65536 floats
  float* p1s = pt  + PSZ;
  float* p3s = p1s + PSZ;
  float* er  = p3s + PSZ;    // [B][K][2][D] = 65536 floats
  // every ws element is written before it is read -> no memset needed

  ucb_k1 <<<B*NSL*TCH, 256, 0, stream>>>(x, mean, variance, pt, p1s, p3s);
  ucb_fin<<<K*(D/16),  256, 0, stream>>>(pt, p1s, p3s, er);
  ucb_k2 <<<B*64,      256, 0, stream>>>(x, mean, variance, er, out);
}